// Round 1
// baseline (235.983 us; speedup 1.0000x reference)
//
#include <hip/hip_runtime.h>

#define KW 11
#define PAD 5
#define TW 32
#define TH 32
#define IW 42              // TW + KW - 1 (column span incl. halo)
#define S4 43              // float4-plane row stride (ODD -> 12*row mod 32 spreads all 8 rows)
#define SX 43              // sx-plane row stride (ODD -> 2-way banks: free)
#define IMH 512
#define IMW 512
#define NBLK 12288         // 16 x 16 x 48

typedef float f2 __attribute__((ext_vector_type(2)));
typedef float f4 __attribute__((ext_vector_type(4)));

// LDS layout: vv4[row*S4 + col] = (mu1, mu2, q11, q22) as one float4 (b128 path)
//             vsx[row*SX + col] = x1*x2 moment (b32 path)
// Bank math (b128 reads, phase B): word-group base = (12*row + 16*(qc&1) + 4*cc) mod 32;
// 12*row mod 32 is distinct for row=0..7 -> 256 word-accesses land 8/bank = data-volume
// minimum, no serialization beyond the inherent 1024B/wave.
// NOTE (R10 lesson): never pass pointers to thread-local arrays — forces
// them to scratch (531 MB spill traffic). wg[] here is only used directly.

template <bool EDGE>
__device__ __forceinline__ void phaseA(
    const float* __restrict__ img1, const float* __restrict__ img2,
    size_t base, int ix0, int iy0, int t, const float* wg,
    f4* __restrict__ vv4, float* __restrict__ vsx)
{
    for (int task = t; task < IW * 8; task += 256) {
        const int c  = task % IW;
        const int rg = task / IW;
        const int gc = ix0 + c;
        const int r0 = rg * 4;
        const int gr0 = iy0 + r0;

        f2 m12[4]  = {{0,0},{0,0},{0,0},{0,0}};   // (mu1, mu2) accumulators
        f2 qq[4]   = {{0,0},{0,0},{0,0},{0,0}};   // (x1^2, x2^2) accumulators
        float sx[4] = {0, 0, 0, 0};               // x1*x2 accumulator
        const bool cvalid = !EDGE || ((gc >= 0) && (gc < IMW));
#pragma unroll
        for (int i = 0; i < 14; ++i) {
            const int gr = gr0 + i;
            f2 x12;
            if (EDGE) {
                const bool ok = cvalid && (gr >= 0) && (gr < IMH);
                const size_t o = base + (size_t)(ok ? gr : 0) * IMW + (ok ? gc : 0);
                x12.x = ok ? img1[o] : 0.f;
                x12.y = ok ? img2[o] : 0.f;
            } else {
                const size_t o = base + (size_t)gr * IMW + gc;
                x12.x = img1[o];
                x12.y = img2[o];
            }
            f2 sq = x12 * x12;                    // packed mul
            float sxy = x12.x * x12.y;
#pragma unroll
            for (int k = 0; k < 4; ++k) {
                const int j = i - k;
                if (j >= 0 && j < KW) {
                    float w = wg[j];
                    f2 w2 = {w, w};
                    m12[k] += w2 * x12;           // v_pk_fma_f32
                    qq[k]  += w2 * sq;            // v_pk_fma_f32
                    sx[k]  += w * sxy;
                }
            }
        }
        const int vb = r0 * S4 + c;
#pragma unroll
        for (int k = 0; k < 4; ++k) {
            f4 v;
            v.x = m12[k].x; v.y = m12[k].y;
            v.z = qq[k].x;  v.w = qq[k].y;
            vv4[vb + k * S4] = v;                 // ds_write_b128
            vsx[r0 * SX + c + k * SX] = sx[k];    // ds_write_b32
        }
    }
}

__global__ __launch_bounds__(256, 5) void ssim_main(
    const float* __restrict__ img1, const float* __restrict__ img2,
    const float* __restrict__ window, float* __restrict__ partial)
{
    __shared__ f4 vv4[TH * S4];          // 22016 B
    __shared__ float vsx[TH * SX];       // 5504 B  -> 27.5 KB total, 5 blocks/CU
    __shared__ float g[KW];
    __shared__ float wsum[4];

    const int t = threadIdx.x;

    // Separable 1D Gaussian = row-sums of the 2D window (columns sum to 1).
    if (t < KW) {
        float s = 0.f;
        for (int j = 0; j < KW; ++j) s += window[(t * KW + j) * 3];
        g[t] = s;
    }
    __syncthreads();

    float wg[KW];
#pragma unroll
    for (int j = 0; j < KW; ++j) wg[j] = g[j];   // broadcast: conflict-free

    const int plane = blockIdx.z;
    const size_t base = (size_t)plane * IMH * IMW;
    const int ix0 = blockIdx.x * TW - PAD;
    const int iy0 = blockIdx.y * TH - PAD;

    // ---- Phase A: vertical 11-tap straight from global (lane<->col coalesced).
    // Interior blocks (76.6%) skip all bounds logic (block-uniform branch).
    const bool interior = (ix0 >= 0) && (ix0 + IW <= IMW) &&
                          (iy0 >= 0) && (iy0 + IW <= IMH);
    if (interior) phaseA<false>(img1, img2, base, ix0, iy0, t, wg, vv4, vsx);
    else          phaseA<true >(img1, img2, base, ix0, iy0, t, wg, vv4, vsx);
    __syncthreads();

    // ---- Phase B: horizontal 11-tap + SSIM; 4 adjacent cols per thread.
    const float C1v = 0.0001f;
    const float C2v = 0.0009f;
    const int row = t >> 3;                       // 0..31
    const int qc = t & 7;                         // col quad 0..7
    const f4* __restrict__ p4 = &vv4[row * S4 + qc * 4];
    const float* __restrict__ px = &vsx[row * SX + qc * 4];
    f2 am12[4] = {{0,0},{0,0},{0,0},{0,0}};
    f2 aqq[4]  = {{0,0},{0,0},{0,0},{0,0}};
    float asx[4] = {0, 0, 0, 0};
#pragma unroll
    for (int cc = 0; cc < 14; ++cc) {
        f4 v = p4[cc];                            // ds_read_b128
        float vx = px[cc];                        // ds_read_b32
        f2 v12 = {v.x, v.y};
        f2 vqq = {v.z, v.w};
#pragma unroll
        for (int k = 0; k < 4; ++k) {
            const int j = cc - k;
            if (j >= 0 && j < KW) {
                float w = wg[j];
                f2 w2 = {w, w};
                am12[k] += w2 * v12;              // v_pk_fma_f32
                aqq[k]  += w2 * vqq;              // v_pk_fma_f32
                asx[k]  += w * vx;
            }
        }
    }
    float lsum = 0.f;
#pragma unroll
    for (int k = 0; k < 4; ++k) {
        float mu1 = am12[k].x, mu2 = am12[k].y;
        float mu1sq = mu1 * mu1, mu2sq = mu2 * mu2, mu12 = mu1 * mu2;
        float sig1 = aqq[k].x - mu1sq;
        float sig2 = aqq[k].y - mu2sq;
        float sig12 = asx[k] - mu12;
        float num = (2.f * mu12 + C1v) * (2.f * sig12 + C2v);
        float den = (mu1sq + mu2sq + C1v) * (sig1 + sig2 + C2v);
        float r = __builtin_amdgcn_rcpf(den);
        r = r * (2.f - den * r);                  // Newton -> ~fp32 exact
        lsum += num * r;
    }

    // ---- Reduction: wave shuffle -> cross-wave LDS -> plain per-block store.
#pragma unroll
    for (int off = 32; off > 0; off >>= 1) lsum += __shfl_down(lsum, off, 64);
    if ((t & 63) == 0) wsum[t >> 6] = lsum;
    __syncthreads();
    if (t == 0) {
        unsigned bid = (blockIdx.z * gridDim.y + blockIdx.y) * gridDim.x
                     + blockIdx.x;
        partial[bid] = wsum[0] + wsum[1] + wsum[2] + wsum[3];
    }
}

__global__ __launch_bounds__(256) void ssim_reduce(
    const float* __restrict__ partial, float* __restrict__ out, double inv_n)
{
    __shared__ double dsum[4];
    const int t = threadIdx.x;
    double s = 0.0;
    for (int i = t; i < NBLK; i += 256) s += (double)partial[i];
#pragma unroll
    for (int off = 32; off > 0; off >>= 1) s += __shfl_down(s, off, 64);
    if ((t & 63) == 0) dsum[t >> 6] = s;
    __syncthreads();
    if (t == 0) out[0] = (float)((dsum[0] + dsum[1] + dsum[2] + dsum[3]) * inv_n);
}

extern "C" void kernel_launch(void* const* d_in, const int* in_sizes, int n_in,
                              void* d_out, int out_size, void* d_ws, size_t ws_size,
                              hipStream_t stream) {
    const float* img1   = (const float*)d_in[0];
    const float* img2   = (const float*)d_in[1];
    const float* window = (const float*)d_in[2];
    float* out = (float*)d_out;
    float* partial = (float*)d_ws;               // 12288 floats = 48 KB

    const int nplanes = in_sizes[0] / (IMH * IMW);   // 48
    const long long total = (long long)in_sizes[0];

    dim3 grid(IMW / TW, IMH / TH, nplanes);      // 16 x 16 x 48 = 12288
    ssim_main<<<grid, 256, 0, stream>>>(img1, img2, window, partial);
    ssim_reduce<<<1, 256, 0, stream>>>(partial, out, 1.0 / (double)total);
}

// Round 2
// 229.096 us; speedup vs baseline: 1.0301x; 1.0301x over previous
//
#include <hip/hip_runtime.h>

#define KW 11
#define PAD 5
#define TW 32
#define TH 32
#define IW 42              // TW + KW - 1 (column span incl. halo)
#define S4 43              // float4-plane row stride (ODD -> 12*row mod 32 spreads all 8 rows)
#define SX 43              // sx-plane row stride (ODD -> 2-way banks: free)
#define IMH 512
#define IMW 512
#define NBLK 12288         // 16 x 16 x 48

typedef float f2 __attribute__((ext_vector_type(2)));
typedef float f4 __attribute__((ext_vector_type(4)));

// LDS layout: vv4[row*S4 + col] = (mu1, mu2, q11, q22) as one float4 (b128 path)
//             vsx[row*SX + col] = x1*x2 moment (b32 path)
// Bank math (b128 reads, phase B): word-group base = (12*row + 16*(qc&1) + 4*cc) mod 32;
// 12*row mod 32 distinct for row=0..7 -> 8 word-accesses/bank = data-volume minimum.
//
// R10/R1 lesson, now actually enforced: wg[] must NEVER have its address
// taken (no function args, no pointers) or it is demoted to scratch
// (R1 counters: WRITE_SIZE 99.6 MB of spill traffic, VGPR stuck at 48).
// Phase A is therefore a macro expanded with a literal EDGE constant.

#define PHASE_A(EDGE_)                                                        \
    for (int task = t; task < IW * 8; task += 256) {                          \
        const int c  = task % IW;                                             \
        const int rg = task / IW;                                             \
        const int gc = ix0 + c;                                               \
        const int r0 = rg * 4;                                                \
        const int gr0 = iy0 + r0;                                             \
        f2 m12[4]  = {{0,0},{0,0},{0,0},{0,0}};                               \
        f2 qq[4]   = {{0,0},{0,0},{0,0},{0,0}};                               \
        float sx[4] = {0, 0, 0, 0};                                           \
        const bool cvalid = !(EDGE_) || ((gc >= 0) && (gc < IMW));            \
        _Pragma("unroll")                                                     \
        for (int i = 0; i < 14; ++i) {                                        \
            const int gr = gr0 + i;                                           \
            f2 x12;                                                           \
            if (EDGE_) {                                                      \
                const bool ok = cvalid && (gr >= 0) && (gr < IMH);            \
                const size_t o = base + (size_t)(ok ? gr : 0) * IMW           \
                               + (ok ? gc : 0);                               \
                x12.x = ok ? img1[o] : 0.f;                                   \
                x12.y = ok ? img2[o] : 0.f;                                   \
            } else {                                                          \
                const size_t o = base + (size_t)gr * IMW + gc;                \
                x12.x = img1[o];                                              \
                x12.y = img2[o];                                              \
            }                                                                 \
            f2 sq = x12 * x12;                                                \
            float sxy = x12.x * x12.y;                                        \
            _Pragma("unroll")                                                 \
            for (int k = 0; k < 4; ++k) {                                     \
                const int j = i - k;                                          \
                if (j >= 0 && j < KW) {                                       \
                    float w = wg[j];                                          \
                    f2 w2 = {w, w};                                           \
                    m12[k] += w2 * x12;                                       \
                    qq[k]  += w2 * sq;                                        \
                    sx[k]  += w * sxy;                                        \
                }                                                             \
            }                                                                 \
        }                                                                     \
        const int vb = r0 * S4 + c;                                           \
        _Pragma("unroll")                                                     \
        for (int k = 0; k < 4; ++k) {                                         \
            f4 v;                                                             \
            v.x = m12[k].x; v.y = m12[k].y;                                   \
            v.z = qq[k].x;  v.w = qq[k].y;                                    \
            vv4[vb + k * S4] = v;                                             \
            vsx[r0 * SX + c + k * SX] = sx[k];                                \
        }                                                                     \
    }

__global__ __launch_bounds__(256, 5) void ssim_main(
    const float* __restrict__ img1, const float* __restrict__ img2,
    const float* __restrict__ window, float* __restrict__ partial)
{
    __shared__ f4 vv4[TH * S4];          // 22016 B
    __shared__ float vsx[TH * SX];       // 5504 B  -> 27.5 KB total, 5 blocks/CU
    __shared__ float g[KW];
    __shared__ float wsum[4];

    const int t = threadIdx.x;

    // Separable 1D Gaussian = row-sums of the 2D window (columns sum to 1).
    if (t < KW) {
        float s = 0.f;
        for (int j = 0; j < KW; ++j) s += window[(t * KW + j) * 3];
        g[t] = s;
    }
    __syncthreads();

    float wg[KW];
#pragma unroll
    for (int j = 0; j < KW; ++j) wg[j] = g[j];   // broadcast: conflict-free

    const int plane = blockIdx.z;
    const size_t base = (size_t)plane * IMH * IMW;
    const int ix0 = blockIdx.x * TW - PAD;
    const int iy0 = blockIdx.y * TH - PAD;

    // ---- Phase A: vertical 11-tap straight from global (lane<->col coalesced).
    // Interior blocks (76.6%) skip all bounds logic (block-uniform branch).
    const bool interior = (ix0 >= 0) && (ix0 + IW <= IMW) &&
                          (iy0 >= 0) && (iy0 + IW <= IMH);
    if (interior) {
        PHASE_A(false)
    } else {
        PHASE_A(true)
    }
    __syncthreads();

    // ---- Phase B: horizontal 11-tap + SSIM; 4 adjacent cols per thread.
    const float C1v = 0.0001f;
    const float C2v = 0.0009f;
    const int row = t >> 3;                       // 0..31
    const int qc = t & 7;                         // col quad 0..7
    const f4* __restrict__ p4 = &vv4[row * S4 + qc * 4];
    const float* __restrict__ px = &vsx[row * SX + qc * 4];
    f2 am12[4] = {{0,0},{0,0},{0,0},{0,0}};
    f2 aqq[4]  = {{0,0},{0,0},{0,0},{0,0}};
    float asx[4] = {0, 0, 0, 0};
#pragma unroll
    for (int cc = 0; cc < 14; ++cc) {
        f4 v = p4[cc];                            // ds_read_b128
        float vx = px[cc];                        // ds_read_b32
        f2 v12 = {v.x, v.y};
        f2 vqq = {v.z, v.w};
#pragma unroll
        for (int k = 0; k < 4; ++k) {
            const int j = cc - k;
            if (j >= 0 && j < KW) {
                float w = wg[j];
                f2 w2 = {w, w};
                am12[k] += w2 * v12;              // v_pk_fma_f32
                aqq[k]  += w2 * vqq;              // v_pk_fma_f32
                asx[k]  += w * vx;
            }
        }
    }
    float lsum = 0.f;
#pragma unroll
    for (int k = 0; k < 4; ++k) {
        float mu1 = am12[k].x, mu2 = am12[k].y;
        float mu1sq = mu1 * mu1, mu2sq = mu2 * mu2, mu12 = mu1 * mu2;
        float sig1 = aqq[k].x - mu1sq;
        float sig2 = aqq[k].y - mu2sq;
        float sig12 = asx[k] - mu12;
        float num = (2.f * mu12 + C1v) * (2.f * sig12 + C2v);
        float den = (mu1sq + mu2sq + C1v) * (sig1 + sig2 + C2v);
        float r = __builtin_amdgcn_rcpf(den);
        r = r * (2.f - den * r);                  // Newton -> ~fp32 exact
        lsum += num * r;
    }

    // ---- Reduction: wave shuffle -> cross-wave LDS -> plain per-block store.
#pragma unroll
    for (int off = 32; off > 0; off >>= 1) lsum += __shfl_down(lsum, off, 64);
    if ((t & 63) == 0) wsum[t >> 6] = lsum;
    __syncthreads();
    if (t == 0) {
        unsigned bid = (blockIdx.z * gridDim.y + blockIdx.y) * gridDim.x
                     + blockIdx.x;
        partial[bid] = wsum[0] + wsum[1] + wsum[2] + wsum[3];
    }
}

__global__ __launch_bounds__(1024) void ssim_reduce(
    const float* __restrict__ partial, float* __restrict__ out, double inv_n)
{
    __shared__ double dsum[16];
    const int t = threadIdx.x;
    double s = 0.0;
    for (int i = t; i < NBLK; i += 1024) s += (double)partial[i];
#pragma unroll
    for (int off = 32; off > 0; off >>= 1) s += __shfl_down(s, off, 64);
    if ((t & 63) == 0) dsum[t >> 6] = s;
    __syncthreads();
    if (t == 0) {
        double tot = 0.0;
#pragma unroll
        for (int w = 0; w < 16; ++w) tot += dsum[w];
        out[0] = (float)(tot * inv_n);
    }
}

extern "C" void kernel_launch(void* const* d_in, const int* in_sizes, int n_in,
                              void* d_out, int out_size, void* d_ws, size_t ws_size,
                              hipStream_t stream) {
    const float* img1   = (const float*)d_in[0];
    const float* img2   = (const float*)d_in[1];
    const float* window = (const float*)d_in[2];
    float* out = (float*)d_out;
    float* partial = (float*)d_ws;               // 12288 floats = 48 KB

    const int nplanes = in_sizes[0] / (IMH * IMW);   // 48
    const long long total = (long long)in_sizes[0];

    dim3 grid(IMW / TW, IMH / TH, nplanes);      // 16 x 16 x 48 = 12288
    ssim_main<<<grid, 256, 0, stream>>>(img1, img2, window, partial);
    ssim_reduce<<<1, 1024, 0, stream>>>(partial, out, 1.0 / (double)total);
}